// Round 1
// baseline (399.370 us; speedup 1.0000x reference)
//
#include <hip/hip_runtime.h>

#define H 512
#define W 960
#define OH 508
#define OW 956
#define NIMG 48

#define OTH 32
#define OTW 32
// input tile: 36x36, stage-1 tile: 34x34

__global__ __launch_bounds__(256) void ssim_kernel(
    const float* __restrict__ x, const float* __restrict__ y,
    float* __restrict__ out)
{
    __shared__ float sx[36][37];
    __shared__ float sy[36][37];
    __shared__ float smux[34][35];
    __shared__ float smuy[34][35];
    __shared__ float sa[34][35];
    __shared__ float sb[34][35];
    __shared__ float sc[34][35];

    const int img = blockIdx.z;
    const int h0 = blockIdx.y * OTH;
    const int w0 = blockIdx.x * OTW;
    const int tid = threadIdx.x;

    const float* __restrict__ xi = x + (size_t)img * H * W;
    const float* __restrict__ yi = y + (size_t)img * H * W;

    // Phase A: load 36x36 halo tiles of x and y into LDS
    for (int i = tid; i < 36 * 36; i += 256) {
        int r = i / 36, c = i % 36;
        int gh = h0 + r, gw = w0 + c;
        bool ok = (gh < H) && (gw < W);
        int idx = gh * W + gw;
        sx[r][c] = ok ? xi[idx] : 0.0f;
        sy[r][c] = ok ? yi[idx] : 0.0f;
    }
    __syncthreads();

    const float inv9 = 1.0f / 9.0f;

    // Phase B: stage-1 (mu_x, mu_y, dx^2, dy^2, dx*dy) on 34x34 grid
    for (int i = tid; i < 34 * 34; i += 256) {
        int p = i / 34, q = i % 34;
        float sxs = 0.f, sys = 0.f;
#pragma unroll
        for (int dp = 0; dp < 3; ++dp) {
#pragma unroll
            for (int dq = 0; dq < 3; ++dq) {
                sxs += sx[p + dp][q + dq];
                sys += sy[p + dp][q + dq];
            }
        }
        float mux = sxs * inv9, muy = sys * inv9;
        float dx = sx[p + 1][q + 1] - mux;
        float dy = sy[p + 1][q + 1] - muy;
        smux[p][q] = mux;
        smuy[p][q] = muy;
        sa[p][q] = dx * dx;
        sb[p][q] = dy * dy;
        sc[p][q] = dx * dy;
    }
    __syncthreads();

    // Phase C: each thread computes 4 outputs (same column, 4 rows)
    const float C1v = 1e-4f, C2v = 9e-4f;
    const int ql = tid & 31;          // output col within tile
    const int pb = (tid >> 5) * 4;    // output row base within tile
    float* __restrict__ oi = out + (size_t)img * OH * OW;

#pragma unroll
    for (int r = 0; r < 4; ++r) {
        int pl = pb + r;
        float s1 = 0.f, s2 = 0.f, s3 = 0.f;
#pragma unroll
        for (int dp = 0; dp < 3; ++dp) {
#pragma unroll
            for (int dq = 0; dq < 3; ++dq) {
                s1 += sa[pl + dp][ql + dq];
                s2 += sb[pl + dp][ql + dq];
                s3 += sc[pl + dp][ql + dq];
            }
        }
        float sigx = s1 * inv9, sigy = s2 * inv9, sigxy = s3 * inv9;
        float mux = smux[pl + 1][ql + 1];
        float muy = smuy[pl + 1][ql + 1];
        float n = (2.f * mux * muy + C1v) * (2.f * sigxy + C2v);
        float d = (mux * mux + muy * muy + C1v) * (sigx + sigy + C2v);
        float v = 1.f - n / d;
        v = fminf(fmaxf(v, 0.f), 2.f);
        int gh = h0 + pl, gw = w0 + ql;
        if (gh < OH && gw < OW)
            oi[gh * OW + gw] = v;
    }
}

extern "C" void kernel_launch(void* const* d_in, const int* in_sizes, int n_in,
                              void* d_out, int out_size, void* d_ws, size_t ws_size,
                              hipStream_t stream) {
    const float* x = (const float*)d_in[0];
    const float* y = (const float*)d_in[1];
    float* out = (float*)d_out;

    dim3 grid((OW + OTW - 1) / OTW,   // 30
              (OH + OTH - 1) / OTH,   // 16
              NIMG);                  // 48
    ssim_kernel<<<grid, 256, 0, stream>>>(x, y, out);
}

// Round 2
// 251.069 us; speedup vs baseline: 1.5907x; 1.5907x over previous
//
#include <hip/hip_runtime.h>

#define H 512
#define W 960
#define OH 508
#define OW 956
#define NIMG 48

#define RH 32                       // output rows per wave
#define WAVES_PER_BLOCK 4
#define ROWS_PER_BLOCK (RH * WAVES_PER_BLOCK)   // 128
#define CW 4                        // output cols per thread
#define STRIPW (64 * CW)            // 256 output cols per wave-strip

// Fully register-resident sliding-window SSIM.
// Thread = 4 output columns; wave = 256-col strip x 32 rows; no LDS, no barriers.
__global__ __launch_bounds__(256) void ssim_kernel(
    const float* __restrict__ x, const float* __restrict__ y,
    float* __restrict__ out)
{
    const int img  = blockIdx.z;
    const int lane = threadIdx.x;                       // 0..63
    const int wv   = threadIdx.y;                       // 0..3
    const int c0   = blockIdx.x * STRIPW;               // 0,256,512,768
    const int h0   = blockIdx.y * ROWS_PER_BLOCK + wv * RH;
    if (h0 >= OH) return;

    const int cb = c0 + lane * CW;                      // output col base
    const bool store_ok = (cb + CW - 1) < OW;           // cb <= 952
    const int cbl = store_ok ? cb : (OW - CW);          // clamped load base (952)

    const float* __restrict__ xi = x + (size_t)img * H * W;
    const float* __restrict__ yi = y + (size_t)img * H * W;
    float* __restrict__ oi = out + (size_t)img * OH * OW;

    // register pipeline state
    float xm1[6], ym1[6];           // prev input row, cols cbl+1..cbl+6 (centers)
    float hxa[6], hxb[6];           // horiz 3-sums of x at rows r-2, r-1
    float hya[6], hyb[6];
    float muxB[6], muyB[6];         // mu at stage-1 row p-1
    float haA[4], haB[4];           // horiz 3-sums of a at stage-1 rows p-2, p-1
    float hbA[4], hbB[4];
    float hcA[4], hcB[4];

    const float inv9 = 1.0f / 9.0f;
    const float C1v = 1e-4f, C2v = 9e-4f;

    const int kmax = min(RH, OH - h0) + 4;   // input rows to stream
    for (int k = 0; k < kmax; ++k) {
        const int r  = h0 + k;
        const int rl = r < H ? r : (H - 1);
        const float4* px = (const float4*)(xi + (size_t)rl * W + cbl);
        const float4* py = (const float4*)(yi + (size_t)rl * W + cbl);
        float4 x4a = px[0], x4b = px[1];
        float4 y4a = py[0], y4b = py[1];
        float xc[8] = {x4a.x, x4a.y, x4a.z, x4a.w, x4b.x, x4b.y, x4b.z, x4b.w};
        float yc[8] = {y4a.x, y4a.y, y4a.z, y4a.w, y4b.x, y4b.y, y4b.z, y4b.w};

        // horizontal 3-sums of this input row
        float hx[6], hy[6];
#pragma unroll
        for (int q = 0; q < 6; ++q) {
            hx[q] = xc[q] + xc[q + 1] + xc[q + 2];
            hy[q] = yc[q] + yc[q + 1] + yc[q + 2];
        }

        float mux[6], muy[6];
        float ha[4], hb[4], hc[4];
        if (k >= 2) {
            // stage-1 row p = r-2
            float a6[6], b6[6], c6[6];
#pragma unroll
            for (int q = 0; q < 6; ++q) {
                mux[q] = (hxa[q] + hxb[q] + hx[q]) * inv9;
                muy[q] = (hya[q] + hyb[q] + hy[q]) * inv9;
                float dx = xm1[q] - mux[q];   // x(r-1, cb+q+1)
                float dy = ym1[q] - muy[q];
                a6[q] = dx * dx;
                b6[q] = dy * dy;
                c6[q] = dx * dy;
            }
#pragma unroll
            for (int w = 0; w < 4; ++w) {
                ha[w] = a6[w] + a6[w + 1] + a6[w + 2];
                hb[w] = b6[w] + b6[w + 1] + b6[w + 2];
                hc[w] = c6[w] + c6[w + 1] + c6[w + 2];
            }

            if (k >= 4) {
                // output row h = p - 2 = r - 4
                const int h = r - 4;
                float4 o;
                float ov[4];
#pragma unroll
                for (int w = 0; w < 4; ++w) {
                    float sigx  = (haA[w] + haB[w] + ha[w]) * inv9;
                    float sigy  = (hbA[w] + hbB[w] + hb[w]) * inv9;
                    float sigxy = (hcA[w] + hcB[w] + hc[w]) * inv9;
                    float mx = muxB[w + 1];   // mu at stage-1 row p-1, col cb+w+1
                    float my = muyB[w + 1];
                    float n = (2.f * mx * my + C1v) * (2.f * sigxy + C2v);
                    float d = (mx * mx + my * my + C1v) * (sigx + sigy + C2v);
                    float v = 1.f - n / d;
                    ov[w] = fminf(fmaxf(v, 0.f), 2.f);
                }
                o.x = ov[0]; o.y = ov[1]; o.z = ov[2]; o.w = ov[3];
                if (store_ok)
                    *(float4*)(oi + (size_t)h * OW + cb) = o;
            }

            // rotate stage-2 histories
#pragma unroll
            for (int w = 0; w < 4; ++w) {
                haA[w] = haB[w]; haB[w] = ha[w];
                hbA[w] = hbB[w]; hbB[w] = hb[w];
                hcA[w] = hcB[w]; hcB[w] = hc[w];
            }
#pragma unroll
            for (int q = 0; q < 6; ++q) {
                muxB[q] = mux[q];
                muyB[q] = muy[q];
            }
        }

        // rotate stage-1 histories
#pragma unroll
        for (int q = 0; q < 6; ++q) {
            hxa[q] = hxb[q]; hxb[q] = hx[q];
            hya[q] = hyb[q]; hyb[q] = hy[q];
            xm1[q] = xc[q + 1];
            ym1[q] = yc[q + 1];
        }
    }
}

extern "C" void kernel_launch(void* const* d_in, const int* in_sizes, int n_in,
                              void* d_out, int out_size, void* d_ws, size_t ws_size,
                              hipStream_t stream) {
    const float* x = (const float*)d_in[0];
    const float* y = (const float*)d_in[1];
    float* out = (float*)d_out;

    dim3 grid((OW + STRIPW - 1) / STRIPW,                 // 4
              (OH + ROWS_PER_BLOCK - 1) / ROWS_PER_BLOCK, // 4
              NIMG);                                      // 48
    dim3 block(64, WAVES_PER_BLOCK, 1);
    ssim_kernel<<<grid, block, 0, stream>>>(x, y, out);
}